// Round 2
// baseline (3887.376 us; speedup 1.0000x reference)
//
#include <hip/hip_runtime.h>
#include <hip/hip_bf16.h>
#include <math.h>

// Problem constants
#define TSTEPS 40
#define GATED  30
#define BATCH  4096
#define XD     150
#define HD     150
#define G4     600      // 4*HD
#define KW     304      // weight row length in global memory (150 x | 150 h | 4 zero)
#define PITCH  308      // LDS [x|h] row pitch: 4*77, 77 odd => conflict-free row groups
#define SGP    601      // LDS gate-preact pitch (odd => conflict-free)
#define S1P    53
#define S2P    27
#define ROWS   8        // batch rows per block
#define NT     512      // 8 waves
#define NBLK   (BATCH / ROWS)   // 512 blocks

// Output packing (flat fp32):
//   outh:    [4096,150]      offset 0
//   outputs: [40,4096,150]   offset 614400
//   ys:      [30,4096,2]     offset 25190400
#define OFF_OUTPUTS 614400
#define OFF_YS      25190400

__device__ __forceinline__ float sigf(float x) {
    return 1.0f / (1.0f + __expf(-x));
}
__device__ __forceinline__ float tanh_fast(float x) {
    x = fminf(fmaxf(x, -15.0f), 15.0f);
    float t = __expf(2.0f * x);
    return (t - 1.0f) / (t + 1.0f);
}

// Pack combined weights into workspace:
//   Wc [600][304]: cols 0..149 = w_ih, 150..299 = w_hh, 300..303 = 0
//   w1c [50][304]: LDS tile is [x | h] but stop-gate input is concat(h, x):
//                  cols 0..149 = w1[j][150+k] (x part), 150..299 = w1[j][k-150] (h part)
//   bc [600] = b_ih + b_hh
__global__ void pack_weights(const float* __restrict__ w_ih, const float* __restrict__ w_hh,
                             const float* __restrict__ b_ih, const float* __restrict__ b_hh,
                             const float* __restrict__ w1,
                             float* __restrict__ Wc, float* __restrict__ w1c,
                             float* __restrict__ bc) {
    int idx = blockIdx.x * blockDim.x + threadIdx.x;
    int stride = gridDim.x * blockDim.x;
    for (int i = idx; i < G4 * KW; i += stride) {
        int j = i / KW, k = i % KW;
        float v = 0.0f;
        if (k < 150)      v = w_ih[j * 150 + k];
        else if (k < 300) v = w_hh[j * 150 + (k - 150)];
        Wc[i] = v;
    }
    for (int i = idx; i < 50 * KW; i += stride) {
        int j = i / KW, k = i % KW;
        float v = 0.0f;
        if (k < 150)      v = w1[j * 300 + 150 + k];   // x part
        else if (k < 300) v = w1[j * 300 + (k - 150)]; // h part
        w1c[i] = v;
    }
    for (int i = idx; i < G4; i += stride) bc[i] = b_ih[i] + b_hh[i];
}

__global__ __launch_bounds__(NT, 4)
void lstm_main(const float* __restrict__ x,
               const float* __restrict__ Wc, const float* __restrict__ bc,
               const float* __restrict__ w1c, const float* __restrict__ b1,
               const float* __restrict__ w2, const float* __restrict__ b2,
               const float* __restrict__ w3, const float* __restrict__ b3,
               float* __restrict__ outh, float* __restrict__ outputs,
               float* __restrict__ ys) {
    __shared__ float sxh[ROWS][PITCH];  // [x(0..149) | h(150..299) | pad(300..307)=0]
    __shared__ float sg[ROWS][SGP];     // gate pre-activations (600 used)
    __shared__ float st1[ROWS][S1P];
    __shared__ float st2[ROWS][S2P];

    const int tid = threadIdx.x;
    const int r  = tid & 7;     // row within block (lanes 0-7 of each j-group)
    const int jj = tid >> 3;    // 0..63: output-column group
    const int row0 = blockIdx.x * ROWS;

    // zero h-part and pads (pads never rewritten; h rewritten each step)
    for (int i = tid; i < ROWS * PITCH; i += NT) {
        int rr = i / PITCH, k = i - rr * PITCH;
        if (k >= 150) sxh[rr][k] = 0.0f;
    }
    // cell state in registers: pair index i = tid + NT*p -> (r=i&7, k=i>>3)
    float creg[3];
#pragma unroll
    for (int m = 0; m < 3; ++m) creg[m] = 0.0f;

    __syncthreads();

    for (int t = 0; t < TSTEPS; ++t) {
        // ---- stage x_t tile into LDS (coalesced float2) ----
        const float* xt = x + ((size_t)t * BATCH + row0) * XD;
        for (int i = tid; i < ROWS * 75; i += NT) {
            int rr = i / 75, kk = i - rr * 75;
            float2 v = *(const float2*)(xt + rr * XD + 2 * kk);
            *(float2*)&sxh[rr][2 * kk] = v;
        }
        __syncthreads();

        // ---- gate GEMV: sg[r][j] = bc[j] + [x|h] . Wc[j], 2-wide j-unroll ----
        {
            const float4* xh4 = (const float4*)(&sxh[r][0]);
            for (int j = jj; j < G4; j += 128) {
                int j2 = j + 64;
                bool has2 = (j2 < G4);
                const float4* w4a = (const float4*)(Wc + (size_t)j * KW);
                const float4* w4b = (const float4*)(Wc + (size_t)(has2 ? j2 : j) * KW);
                float ax = 0.f, ay = 0.f, az = 0.f, aw = 0.f;
                float bx = 0.f, by = 0.f, bz = 0.f, bw = 0.f;
#pragma unroll 4
                for (int kk = 0; kk < KW / 4; ++kk) {
                    float4 v  = xh4[kk];
                    float4 wa = w4a[kk];
                    float4 wb = w4b[kk];
                    ax = fmaf(wa.x, v.x, ax);
                    ay = fmaf(wa.y, v.y, ay);
                    az = fmaf(wa.z, v.z, az);
                    aw = fmaf(wa.w, v.w, aw);
                    bx = fmaf(wb.x, v.x, bx);
                    by = fmaf(wb.y, v.y, by);
                    bz = fmaf(wb.z, v.z, bz);
                    bw = fmaf(wb.w, v.w, bw);
                }
                sg[r][j] = bc[j] + ((ax + ay) + (az + aw));
                if (has2) sg[r][j2] = bc[j2] + ((bx + by) + (bz + bw));
            }
        }
        __syncthreads();

        // ---- pointwise LSTM cell update (gate order i,f,g,o) ----
        {
            int p = 0;
            for (int i = tid; i < ROWS * HD; i += NT, ++p) {
                int rr = i & 7, k = i >> 3;
                float gi = sg[rr][k];
                float gf = sg[rr][150 + k];
                float gg = sg[rr][300 + k];
                float go = sg[rr][450 + k];
                float cn = sigf(gf) * creg[p] + sigf(gi) * tanh_fast(gg);
                creg[p] = cn;
                sxh[rr][150 + k] = sigf(go) * tanh_fast(cn);
            }
        }
        __syncthreads();

        // ---- coalesced copy of h to outputs (and outh at t==29) ----
        for (int i = tid; i < ROWS * 75; i += NT) {
            int rr = i / 75, kk = i - rr * 75;
            float2 v = *(const float2*)&sxh[rr][150 + 2 * kk];
            *(float2*)(outputs + ((size_t)t * BATCH + row0 + rr) * HD + 2 * kk) = v;
            if (t == GATED - 1) {
                *(float2*)(outh + (size_t)(row0 + rr) * HD + 2 * kk) = v;
            }
        }

        if (t < GATED) {
            // ---- stop gate layer 1: [x|h] . w1c[j] -> relu (400 tasks) ----
            if (tid < ROWS * 50) {
                int rr = tid & 7, j = tid >> 3;
                const float4* w4  = (const float4*)(w1c + (size_t)j * KW);
                const float4* xh4 = (const float4*)(&sxh[rr][0]);
                float ax = 0.f, ay = 0.f, az = 0.f, aw = 0.f;
#pragma unroll 4
                for (int kk = 0; kk < KW / 4; ++kk) {
                    float4 w = w4[kk];
                    float4 v = xh4[kk];
                    ax = fmaf(w.x, v.x, ax);
                    ay = fmaf(w.y, v.y, ay);
                    az = fmaf(w.z, v.z, az);
                    aw = fmaf(w.w, v.w, aw);
                }
                float s = b1[j] + ((ax + ay) + (az + aw));
                st1[rr][j] = s > 0.0f ? s : 0.0f;
            }
            __syncthreads();

            // ---- layer 2: 25 outputs, dot-50 (200 tasks) ----
            if (tid < ROWS * 25) {
                int rr = tid & 7, j = tid >> 3;
                float a = b2[j];
                for (int k2 = 0; k2 < 50; ++k2)
                    a = fmaf(w2[j * 50 + k2], st1[rr][k2], a);
                st2[rr][j] = a > 0.0f ? a : 0.0f;
            }
            __syncthreads();

            // ---- layer 3 + relu + softmax(2) ----
            if (tid < ROWS) {
                int rr = tid;
                float z0 = b3[0], z1 = b3[1];
                for (int k2 = 0; k2 < 25; ++k2) {
                    z0 = fmaf(w3[k2],      st2[rr][k2], z0);
                    z1 = fmaf(w3[25 + k2], st2[rr][k2], z1);
                }
                z0 = z0 > 0.0f ? z0 : 0.0f;
                z1 = z1 > 0.0f ? z1 : 0.0f;
                float mx = fmaxf(z0, z1);
                float e0 = __expf(z0 - mx), e1 = __expf(z1 - mx);
                float inv = 1.0f / (e0 + e1);
                size_t yb = ((size_t)t * BATCH + row0 + rr) * 2;
                ys[yb]     = e0 * inv;
                ys[yb + 1] = e1 * inv;
            }
            // no sync needed here: next phases that touch st2/st1 are separated
            // by the x-load and gate syncs of the next iteration
        }
    }
}

extern "C" void kernel_launch(void* const* d_in, const int* in_sizes, int n_in,
                              void* d_out, int out_size, void* d_ws, size_t ws_size,
                              hipStream_t stream) {
    const float* x    = (const float*)d_in[0];
    const float* w_ih = (const float*)d_in[1];
    const float* w_hh = (const float*)d_in[2];
    const float* b_ih = (const float*)d_in[3];
    const float* b_hh = (const float*)d_in[4];
    const float* w1   = (const float*)d_in[5];
    const float* b1   = (const float*)d_in[6];
    const float* w2   = (const float*)d_in[7];
    const float* b2   = (const float*)d_in[8];
    const float* w3   = (const float*)d_in[9];
    const float* b3   = (const float*)d_in[10];

    float* out = (float*)d_out;
    float* ws  = (float*)d_ws;
    float* Wc  = ws;                         // 600*304
    float* w1c = ws + G4 * KW;               // 50*304
    float* bc  = ws + G4 * KW + 50 * KW;     // 600

    pack_weights<<<256, 256, 0, stream>>>(w_ih, w_hh, b_ih, b_hh, w1, Wc, w1c, bc);

    lstm_main<<<NBLK, NT, 0, stream>>>(
        x, Wc, bc, w1c, b1, w2, b2, w3, b3,
        out, out + OFF_OUTPUTS, out + OFF_YS);
}

// Round 3
// 694.425 us; speedup vs baseline: 5.5980x; 5.5980x over previous
//
#include <hip/hip_runtime.h>
#include <hip/hip_bf16.h>
#include <math.h>

// ---------------- problem constants ----------------
#define TSTEPS 40
#define GATED  30
#define BATCH  4096
#define XD     150
#define HD     150
#define HP     160      // padded hidden/x dim
#define KA     320      // MFMA K = x(160) + h(160)
#define PITCHW 328      // Wc row pitch (bf16 elems, 656 B, 16B-aligned)
#define SXP    328      // sxh row pitch (bf16 elems)
#define NGT    40       // gate tiles (640 rows / 16)
#define NWT    4        // w1 tiles   (64 rows / 16)
#define WROWS  704      // (NGT+NWT)*16
#define SGP    705      // sg pitch (fp32), odd
#define ROWS   16       // batch rows per block (MFMA M)
#define NT     512      // 8 waves
#define NBLK   (BATCH / ROWS)  // 256

// output packing (flat fp32)
#define OFF_OUTPUTS 614400
#define OFF_YS      25190400

typedef float  floatx4 __attribute__((ext_vector_type(4)));
typedef short  shortx8 __attribute__((ext_vector_type(8)));

__device__ __forceinline__ unsigned short bf16_rne(float f) {
    union { float f; unsigned int u; } v; v.f = f;
    unsigned int u = v.u;
    return (unsigned short)((u + 0x7fffu + ((u >> 16) & 1u)) >> 16);
}
__device__ __forceinline__ float sigf(float x) {
    return 1.0f / (1.0f + __expf(-x));
}
__device__ __forceinline__ float tanh_fast(float x) {
    x = fminf(fmaxf(x, -15.0f), 15.0f);
    float t = __expf(2.0f * x);
    return (t - 1.0f) / (t + 1.0f);
}

// ---------------- weight packing ----------------
// Wc [704][328] bf16:
//   rows 0..639: gate rows, type-major: row = tp*160+u  <- gates row tp*150+u (u<150)
//     cols 0..159  : w_ih[., k]   (k<150, else 0)
//     cols 160..319: w_hh[., k-160]
//     cols 320..327: 0
//   rows 640..703: w1 rows (j<50): x-part cols 0..149 = w1[j][150+k]; h-part cols 160..309 = w1[j][k-160]
// bcp [640] fp32 = padded (b_ih + b_hh); b1p [64] fp32 = padded b1
__global__ void pack_weights(const float* __restrict__ w_ih, const float* __restrict__ w_hh,
                             const float* __restrict__ b_ih, const float* __restrict__ b_hh,
                             const float* __restrict__ w1,
                             unsigned short* __restrict__ Wc,
                             float* __restrict__ bcp, float* __restrict__ b1p) {
    int idx = blockIdx.x * blockDim.x + threadIdx.x;
    int stride = gridDim.x * blockDim.x;
    for (int i = idx; i < WROWS * PITCHW; i += stride) {
        int j = i / PITCHW, k = i - j * PITCHW;
        float v = 0.0f;
        if (j < 640) {
            int tp = j / HP, u = j - tp * HP;
            if (u < 150) {
                int src = tp * 150 + u;
                if (k < 150)                    v = w_ih[src * 150 + k];
                else if (k >= 160 && k < 310)   v = w_hh[src * 150 + (k - 160)];
            }
        } else {
            int j1 = j - 640;
            if (j1 < 50) {
                if (k < 150)                    v = w1[j1 * 300 + 150 + k];   // x part
                else if (k >= 160 && k < 310)   v = w1[j1 * 300 + (k - 160)]; // h part
            }
        }
        Wc[i] = bf16_rne(v);
    }
    for (int i = idx; i < 640; i += stride) {
        int tp = i / HP, u = i - tp * HP;
        bcp[i] = (u < 150) ? (b_ih[tp * 150 + u] + b_hh[tp * 150 + u]) : 0.0f;
    }
    for (int i = idx; i < 64; i += stride)
        b1p[i] = (i < 50) ? w1 == nullptr ? 0.0f : 0.0f + ((const float*)b1p, 0.0f) : 0.0f; // placeholder (overwritten below)
}

// b1 copy kept separate for clarity (different input pointer)
__global__ void pack_b1(const float* __restrict__ b1, float* __restrict__ b1p) {
    int i = threadIdx.x;
    if (i < 64) b1p[i] = (i < 50) ? b1[i] : 0.0f;
}

// ---------------- main persistent LSTM kernel ----------------
__global__ __launch_bounds__(NT, 2)
void lstm_main(const float* __restrict__ x,
               const unsigned short* __restrict__ Wc,
               const float* __restrict__ bcp, const float* __restrict__ b1p,
               const float* __restrict__ w2, const float* __restrict__ b2,
               const float* __restrict__ w3, const float* __restrict__ b3,
               float* __restrict__ outh, float* __restrict__ outputs,
               float* __restrict__ ys) {
    __shared__ unsigned short sxh[ROWS][SXP]; // bf16 [x(0..149)|0|h(160..309)|0]
    __shared__ float sg[ROWS][SGP];           // MFMA out: 640 gates + 64 w1
    __shared__ float st1[ROWS][65];
    __shared__ float st2[ROWS][27];
    __shared__ float bcs[640], b1s[64];
    __shared__ float sw2[1250], sb2[25], sw3[50], sb3[2];

    const int tid  = threadIdx.x;
    const int lane = tid & 63;
    const int wv   = tid >> 6;     // wave 0..7
    const int lrow = lane & 15;    // A/B row within tile
    const int lq   = lane >> 4;    // quad 0..3
    const int row0 = blockIdx.x * ROWS;

    // ---- one-time init ----
    for (int i = tid; i < ROWS * SXP; i += NT) {
        int r = i / SXP, k = i - r * SXP;
        if (k >= 150) sxh[r][k] = 0;   // h=0, pads=0 (x region staged each step)
    }
    for (int i = tid; i < 640; i += NT) bcs[i] = bcp[i];
    if (tid < 64) b1s[tid] = b1p[tid];
    for (int i = tid; i < 1250; i += NT) sw2[i] = w2[i];
    if (tid < 25) sb2[tid] = b2[tid];
    if (tid < 50) sw3[tid] = w3[tid];
    if (tid < 2)  sb3[tid] = b3[tid];

    float creg[5];
#pragma unroll
    for (int p = 0; p < 5; ++p) creg[p] = 0.0f;

    __syncthreads();

    for (int t = 0; t < TSTEPS; ++t) {
        // ---- stage x_t (fp32 -> bf16) into sxh[.][0..149] ----
        const float* xt = x + ((size_t)t * BATCH + row0) * XD;
        for (int i = tid; i < ROWS * 75; i += NT) {
            int rr = i / 75, kk = i - rr * 75;
            float2 v = *(const float2*)(xt + rr * XD + 2 * kk);
            unsigned int pk = (unsigned int)bf16_rne(v.x) |
                              ((unsigned int)bf16_rne(v.y) << 16);
            *(unsigned int*)&sxh[rr][2 * kk] = pk;
        }
        __syncthreads();   // B1: x staged, h from prev step present

        // ---- A-fragments: xh row lrow, 10 K-blocks of 32 ----
        shortx8 afr[10];
#pragma unroll
        for (int kb = 0; kb < 10; ++kb)
            afr[kb] = *(const shortx8*)&sxh[lrow][kb * 32 + lq * 8];

        // ---- gate tiles: wave wv handles tiles wv, wv+8, ..., wv+32 ----
#pragma unroll
        for (int it = 0; it < 5; ++it) {
            const int T = wv + 8 * it;
            const unsigned short* wb = Wc + (size_t)(T * 16 + lrow) * PITCHW + lq * 8;
            floatx4 acc0 = {0.f, 0.f, 0.f, 0.f};
            floatx4 acc1 = {0.f, 0.f, 0.f, 0.f};
#pragma unroll
            for (int kb = 0; kb < 10; kb += 2) {
                shortx8 b0 = *(const shortx8*)(wb + kb * 32);
                shortx8 b1v = *(const shortx8*)(wb + (kb + 1) * 32);
                acc0 = __builtin_amdgcn_mfma_f32_16x16x32_bf16(afr[kb], b0, acc0, 0, 0, 0);
                acc1 = __builtin_amdgcn_mfma_f32_16x16x32_bf16(afr[kb + 1], b1v, acc1, 0, 0, 0);
            }
            floatx4 acc = acc0 + acc1;
            const int colb = T * 16 + lrow;
#pragma unroll
            for (int rg = 0; rg < 4; ++rg)
                sg[lq * 4 + rg][colb] = acc[rg];
        }
        __syncthreads();   // B2: all gate pre-activations in sg

        // ---- pointwise cell update: e = (r,u), u in [0,160) ----
#pragma unroll
        for (int p = 0; p < 5; ++p) {
            int e = tid + NT * p;
            int r = e / HP, u = e - r * HP;
            float gi = sg[r][u]        + bcs[u];
            float gf = sg[r][HP + u]   + bcs[HP + u];
            float gg = sg[r][2*HP + u] + bcs[2*HP + u];
            float go = sg[r][3*HP + u] + bcs[3*HP + u];
            float cn = sigf(gf) * creg[p] + sigf(gi) * tanh_fast(gg);
            creg[p] = cn;
            float h = sigf(go) * tanh_fast(cn);
            sxh[r][HP + u] = bf16_rne(h);   // h for next step (pad u>=150 writes 0)
            if (u < 150) {
                outputs[((size_t)t * BATCH + row0 + r) * HD + u] = h;
                if (t == GATED - 1)
                    outh[(size_t)(row0 + r) * HD + u] = h;
            }
        }
        __syncthreads();   // B3: new h in sxh

        if (t < GATED) {
            // ---- w1 tiles (need NEW h): waves 0..3, tiles 40..43 ----
            if (wv < 4) {
                shortx8 af2[10];
#pragma unroll
                for (int kb = 0; kb < 10; ++kb)
                    af2[kb] = *(const shortx8*)&sxh[lrow][kb * 32 + lq * 8];
                const int T = NGT + wv;
                const unsigned short* wb = Wc + (size_t)(T * 16 + lrow) * PITCHW + lq * 8;
                floatx4 acc0 = {0.f, 0.f, 0.f, 0.f};
                floatx4 acc1 = {0.f, 0.f, 0.f, 0.f};
#pragma unroll
                for (int kb = 0; kb < 10; kb += 2) {
                    shortx8 b0 = *(const shortx8*)(wb + kb * 32);
                    shortx8 b1v = *(const shortx8*)(wb + (kb + 1) * 32);
                    acc0 = __builtin_amdgcn_mfma_f32_16x16x32_bf16(af2[kb], b0, acc0, 0, 0, 0);
                    acc1 = __builtin_amdgcn_mfma_f32_16x16x32_bf16(af2[kb + 1], b1v, acc1, 0, 0, 0);
                }
                floatx4 acc = acc0 + acc1;
                const int colb = T * 16 + lrow;
#pragma unroll
                for (int rg = 0; rg < 4; ++rg)
                    sg[lq * 4 + rg][colb] = acc[rg];
            }
            __syncthreads();   // B4: w1 pre-activations ready

            // ---- layer1 relu -> st1 (16 x 64 tasks) ----
#pragma unroll
            for (int p = 0; p < 2; ++p) {
                int e = tid + NT * p;
                int r = e >> 6, j = e & 63;
                float s = sg[r][640 + j] + b1s[j];
                st1[r][j] = s > 0.0f ? s : 0.0f;
            }
            __syncthreads();   // B5

            // ---- layer2: 16 x 25, dot-50 ----
            if (tid < ROWS * 25) {
                int r = tid / 25, j = tid - r * 25;
                float a = sb2[j];
                const float* w2r = &sw2[j * 50];
#pragma unroll 10
                for (int k2 = 0; k2 < 50; ++k2)
                    a = fmaf(w2r[k2], st1[r][k2], a);
                st2[r][j] = a > 0.0f ? a : 0.0f;
            }
            __syncthreads();   // B6

            // ---- layer3 + relu + softmax(2) ----
            if (tid < ROWS) {
                int r = tid;
                float z0 = sb3[0], z1 = sb3[1];
#pragma unroll
                for (int k2 = 0; k2 < 25; ++k2) {
                    z0 = fmaf(sw3[k2],      st2[r][k2], z0);
                    z1 = fmaf(sw3[25 + k2], st2[r][k2], z1);
                }
                z0 = z0 > 0.0f ? z0 : 0.0f;
                z1 = z1 > 0.0f ? z1 : 0.0f;
                float mx = fmaxf(z0, z1);
                float e0 = __expf(z0 - mx), e1 = __expf(z1 - mx);
                float inv = 1.0f / (e0 + e1);
                size_t yb = ((size_t)t * BATCH + row0 + r) * 2;
                ys[yb]     = e0 * inv;
                ys[yb + 1] = e1 * inv;
            }
            // no barrier: st1/st2 next written >=2 barriers into next iter
        }
    }
}

extern "C" void kernel_launch(void* const* d_in, const int* in_sizes, int n_in,
                              void* d_out, int out_size, void* d_ws, size_t ws_size,
                              hipStream_t stream) {
    const float* x    = (const float*)d_in[0];
    const float* w_ih = (const float*)d_in[1];
    const float* w_hh = (const float*)d_in[2];
    const float* b_ih = (const float*)d_in[3];
    const float* b_hh = (const float*)d_in[4];
    const float* w1   = (const float*)d_in[5];
    const float* b1   = (const float*)d_in[6];
    const float* w2   = (const float*)d_in[7];
    const float* b2   = (const float*)d_in[8];
    const float* w3   = (const float*)d_in[9];
    const float* b3   = (const float*)d_in[10];

    float* out = (float*)d_out;
    // workspace layout
    unsigned short* Wc  = (unsigned short*)d_ws;           // 704*328 bf16
    float*          bcp = (float*)(Wc + WROWS * PITCHW);   // 640
    float*          b1p = bcp + 640;                       // 64

    pack_weights<<<256, 256, 0, stream>>>(w_ih, w_hh, b_ih, b_hh, w1, Wc, bcp, b1p);
    pack_b1<<<1, 64, 0, stream>>>(b1, b1p);

    lstm_main<<<NBLK, NT, 0, stream>>>(
        x, Wc, bcp, b1p, w2, b2, w3, b3,
        out, out + OFF_OUTPUTS, out + OFF_YS);
}

// Round 4
// 576.270 us; speedup vs baseline: 6.7458x; 1.2050x over previous
//
#include <hip/hip_runtime.h>
#include <hip/hip_bf16.h>
#include <math.h>

// ---------------- problem constants ----------------
#define TSTEPS 40
#define GATED  30
#define BATCH  4096
#define XD     150
#define HD     150
#define HP     160      // padded hidden/x dim
#define PITCHW 328      // Wc row pitch (bf16 elems, 656 B)
#define SXP    328      // sxh row pitch (bf16 elems)
#define NGT    40       // gate tiles (640 rows / 16)
#define WROWS  704      // 640 gate rows + 64 w1 rows
#define SGP    643      // sg pitch (fp32)
#define W1P    68       // w1 partial-sum pitch
#define ROWS   16       // batch rows per block (MFMA M)
#define NT     512      // 8 waves
#define NBLK   (BATCH / ROWS)  // 256 blocks -> 1 per CU (VGPR-limited)

// output packing (flat fp32)
#define OFF_OUTPUTS 614400
#define OFF_YS      25190400

typedef float  floatx4 __attribute__((ext_vector_type(4)));
typedef short  shortx8 __attribute__((ext_vector_type(8)));

__device__ __forceinline__ unsigned short bf16_rne(float f) {
    union { float f; unsigned int u; } v; v.f = f;
    unsigned int u = v.u;
    return (unsigned short)((u + 0x7fffu + ((u >> 16) & 1u)) >> 16);
}
__device__ __forceinline__ float sigf(float x) {
    return 1.0f / (1.0f + __expf(-x));
}
__device__ __forceinline__ float tanh_fast(float x) {
    x = fminf(fmaxf(x, -15.0f), 15.0f);
    float t = __expf(2.0f * x);
    return (t - 1.0f) / (t + 1.0f);
}

// ---------------- weight packing ----------------
// Wc [704][328] bf16:
//   rows 0..639: gate rows, type-major: row = tp*160+u  <- gate row tp*150+u (u<150)
//     cols 0..149 = w_ih, cols 160..309 = w_hh, rest 0
//   rows 640..703: w1 rows (j<50): cols 0..149 = w1[j][150+k] (x part),
//                                  cols 160..309 = w1[j][k-160] (h part)
// bcp [640] = padded (b_ih + b_hh)
__global__ void pack_weights(const float* __restrict__ w_ih, const float* __restrict__ w_hh,
                             const float* __restrict__ b_ih, const float* __restrict__ b_hh,
                             const float* __restrict__ w1,
                             unsigned short* __restrict__ Wc, float* __restrict__ bcp) {
    int idx = blockIdx.x * blockDim.x + threadIdx.x;
    int stride = gridDim.x * blockDim.x;
    for (int i = idx; i < WROWS * PITCHW; i += stride) {
        int j = i / PITCHW, k = i - j * PITCHW;
        float v = 0.0f;
        if (j < 640) {
            int tp = j / HP, u = j - tp * HP;
            if (u < 150) {
                int src = tp * 150 + u;
                if (k < 150)                    v = w_ih[src * 150 + k];
                else if (k >= 160 && k < 310)   v = w_hh[src * 150 + (k - 160)];
            }
        } else {
            int j1 = j - 640;
            if (j1 < 50) {
                if (k < 150)                    v = w1[j1 * 300 + 150 + k];   // x part
                else if (k >= 160 && k < 310)   v = w1[j1 * 300 + (k - 160)]; // h part
            }
        }
        Wc[i] = bf16_rne(v);
    }
    for (int i = idx; i < 640; i += stride) {
        int tp = i / HP, u = i - tp * HP;
        bcp[i] = (u < 150) ? (b_ih[tp * 150 + u] + b_hh[tp * 150 + u]) : 0.0f;
    }
}

// ---------------- main persistent LSTM kernel ----------------
__global__ __launch_bounds__(NT, 2)
void lstm_main(const float* __restrict__ x,
               const unsigned short* __restrict__ Wc,
               const float* __restrict__ bcp, const float* __restrict__ b1,
               const float* __restrict__ w2, const float* __restrict__ b2,
               const float* __restrict__ w3, const float* __restrict__ b3,
               float* __restrict__ outh, float* __restrict__ outputs,
               float* __restrict__ ys) {
    __shared__ unsigned short sxh[ROWS][SXP]; // bf16 [x(0..149)|0|h(160..309)|0]
    __shared__ float sg[ROWS][SGP];           // gate pre-activations (640 used)
    __shared__ float sgw1a[ROWS][W1P];        // w1 x-part partial
    __shared__ float sgw1b[ROWS][W1P];        // w1 h-part partial
    __shared__ float st1[ROWS][65];
    __shared__ float st2[ROWS][27];
    __shared__ float bcs[640], b1s[64];
    __shared__ float sw2[1250], sb2[25], sw3[50], sb3[2];

    const int tid  = threadIdx.x;
    const int lane = tid & 63;
    const int wv   = tid >> 6;     // wave 0..7
    const int lrow = lane & 15;    // tile row (N for B, M for A)
    const int lq   = lane >> 4;    // quad 0..3
    const int row0 = blockIdx.x * ROWS;

    // ---- one-time init ----
    for (int i = tid; i < ROWS * SXP; i += NT) {
        int r = i / SXP, k = i - r * SXP;
        if (k >= 150) sxh[r][k] = 0;   // h=0, pads=0
    }
    for (int i = tid; i < 640; i += NT) bcs[i] = bcp[i];
    if (tid < 64) b1s[tid] = (tid < 50) ? b1[tid] : 0.0f;
    for (int i = tid; i < 1250; i += NT) sw2[i] = w2[i];
    if (tid < 25) sb2[tid] = b2[tid];
    if (tid < 50) sw3[tid] = w3[tid];
    if (tid < 2)  sb3[tid] = b3[tid];

    // ---- load this wave's 5 gate tiles into registers (stay for all 40 steps) ----
    // tile T = wv + 8*it; B-frag: Wc row (T*16+lrow), shorts [kb*32+lq*8 .. +8)
    shortx8 bfr[50];
#pragma unroll
    for (int it = 0; it < 5; ++it) {
        const unsigned short* wp =
            Wc + (size_t)((wv + 8 * it) * 16 + lrow) * PITCHW + lq * 8;
#pragma unroll
        for (int kb = 0; kb < 10; ++kb)
            bfr[it * 10 + kb] = *(const shortx8*)(wp + kb * 32);
    }

    float creg[5];
#pragma unroll
    for (int p = 0; p < 5; ++p) creg[p] = 0.0f;

    __syncthreads();

    for (int t = 0; t < TSTEPS; ++t) {
        // ---- stage x_t (fp32 -> bf16) into sxh[.][0..149] ----
        const float* xt = x + ((size_t)t * BATCH + row0) * XD;
        for (int i = tid; i < ROWS * 75; i += NT) {
            int rr = i / 75, kk = i - rr * 75;
            float2 v = *(const float2*)(xt + rr * XD + 2 * kk);
            unsigned int pk = (unsigned int)bf16_rne(v.x) |
                              ((unsigned int)bf16_rne(v.y) << 16);
            *(unsigned int*)&sxh[rr][2 * kk] = pk;
        }
        __syncthreads();   // B1: x staged, h present

        // ---- gate MFMAs: kb-outer, weights from registers ----
        {
            floatx4 acc[5];
#pragma unroll
            for (int it = 0; it < 5; ++it) acc[it] = (floatx4){0.f, 0.f, 0.f, 0.f};
#pragma unroll
            for (int kb = 0; kb < 10; ++kb) {
                shortx8 a = *(const shortx8*)&sxh[lrow][kb * 32 + lq * 8];
#pragma unroll
                for (int it = 0; it < 5; ++it)
                    acc[it] = __builtin_amdgcn_mfma_f32_16x16x32_bf16(
                        a, bfr[it * 10 + kb], acc[it], 0, 0, 0);
            }
#pragma unroll
            for (int it = 0; it < 5; ++it) {
                const int colb = (wv + 8 * it) * 16 + lrow;
#pragma unroll
                for (int rg = 0; rg < 4; ++rg)
                    sg[lq * 4 + rg][colb] = acc[it][rg];
            }
        }
        __syncthreads();   // B2: gate pre-acts in sg

        // ---- pointwise cell update (i,f,g,o), h -> sxh + outputs ----
#pragma unroll
        for (int p = 0; p < 5; ++p) {
            int e = tid + NT * p;
            int r = e / HP, u = e - r * HP;
            float gi = sg[r][u]          + bcs[u];
            float gf = sg[r][HP + u]     + bcs[HP + u];
            float gg = sg[r][2 * HP + u] + bcs[2 * HP + u];
            float go = sg[r][3 * HP + u] + bcs[3 * HP + u];
            float cn = sigf(gf) * creg[p] + sigf(gi) * tanh_fast(gg);
            creg[p] = cn;
            float h = sigf(go) * tanh_fast(cn);
            sxh[r][HP + u] = bf16_rne(h);
            if (u < 150) {
                outputs[((size_t)t * BATCH + row0 + r) * HD + u] = h;
                if (t == GATED - 1)
                    outh[(size_t)(row0 + r) * HD + u] = h;
            }
        }
        __syncthreads();   // B3: new h in sxh

        if (t < GATED) {
            // ---- w1 MFMAs (streamed from L2; needs NEW h) ----
            // wave wv: half = wv>>2 (0: x cols 0..159, 1: h cols 160..319), tile tw = wv&3
            {
                const int half = wv >> 2;
                const int tw   = wv & 3;
                const unsigned short* wp1 =
                    Wc + (size_t)(640 + tw * 16 + lrow) * PITCHW + half * 160 + lq * 8;
                shortx8 wf0 = *(const shortx8*)(wp1);
                shortx8 wf1 = *(const shortx8*)(wp1 + 32);
                shortx8 wf2 = *(const shortx8*)(wp1 + 64);
                shortx8 wf3 = *(const shortx8*)(wp1 + 96);
                shortx8 wf4 = *(const shortx8*)(wp1 + 128);
                const int abase = half * 160 + lq * 8;
                floatx4 aw = {0.f, 0.f, 0.f, 0.f};
                shortx8 a0 = *(const shortx8*)&sxh[lrow][abase];
                aw = __builtin_amdgcn_mfma_f32_16x16x32_bf16(a0, wf0, aw, 0, 0, 0);
                a0 = *(const shortx8*)&sxh[lrow][abase + 32];
                aw = __builtin_amdgcn_mfma_f32_16x16x32_bf16(a0, wf1, aw, 0, 0, 0);
                a0 = *(const shortx8*)&sxh[lrow][abase + 64];
                aw = __builtin_amdgcn_mfma_f32_16x16x32_bf16(a0, wf2, aw, 0, 0, 0);
                a0 = *(const shortx8*)&sxh[lrow][abase + 96];
                aw = __builtin_amdgcn_mfma_f32_16x16x32_bf16(a0, wf3, aw, 0, 0, 0);
                a0 = *(const shortx8*)&sxh[lrow][abase + 128];
                aw = __builtin_amdgcn_mfma_f32_16x16x32_bf16(a0, wf4, aw, 0, 0, 0);
                float* dst = half ? &sgw1b[0][0] : &sgw1a[0][0];
                const int colb = tw * 16 + lrow;
#pragma unroll
                for (int rg = 0; rg < 4; ++rg)
                    dst[(lq * 4 + rg) * W1P + colb] = aw[rg];
            }
            __syncthreads();   // B4: w1 partials ready

            // ---- layer1 relu -> st1 (16 x 64) ----
#pragma unroll
            for (int p = 0; p < 2; ++p) {
                int e = tid + NT * p;
                int r = e >> 6, j = e & 63;
                float s = sgw1a[r][j] + sgw1b[r][j] + b1s[j];
                st1[r][j] = s > 0.0f ? s : 0.0f;
            }
            __syncthreads();   // B5

            // ---- layer2: 16 x 25, dot-50 ----
            if (tid < ROWS * 25) {
                int r = tid / 25, j = tid - r * 25;
                float a = sb2[j];
                const float* w2r = &sw2[j * 50];
#pragma unroll 10
                for (int k2 = 0; k2 < 50; ++k2)
                    a = fmaf(w2r[k2], st1[r][k2], a);
                st2[r][j] = a > 0.0f ? a : 0.0f;
            }
            __syncthreads();   // B6

            // ---- layer3 + relu + softmax(2) ----
            if (tid < ROWS) {
                int r = tid;
                float z0 = sb3[0], z1 = sb3[1];
#pragma unroll
                for (int k2 = 0; k2 < 25; ++k2) {
                    z0 = fmaf(sw3[k2],      st2[r][k2], z0);
                    z1 = fmaf(sw3[25 + k2], st2[r][k2], z1);
                }
                z0 = z0 > 0.0f ? z0 : 0.0f;
                z1 = z1 > 0.0f ? z1 : 0.0f;
                float mx = fmaxf(z0, z1);
                float e0 = __expf(z0 - mx), e1 = __expf(z1 - mx);
                float inv = 1.0f / (e0 + e1);
                size_t yb = ((size_t)t * BATCH + row0 + r) * 2;
                ys[yb]     = e0 * inv;
                ys[yb + 1] = e1 * inv;
            }
            // st1/st2/sgw1* not rewritten until after B4 of next iteration -> safe
        }
    }
}

extern "C" void kernel_launch(void* const* d_in, const int* in_sizes, int n_in,
                              void* d_out, int out_size, void* d_ws, size_t ws_size,
                              hipStream_t stream) {
    const float* x    = (const float*)d_in[0];
    const float* w_ih = (const float*)d_in[1];
    const float* w_hh = (const float*)d_in[2];
    const float* b_ih = (const float*)d_in[3];
    const float* b_hh = (const float*)d_in[4];
    const float* w1   = (const float*)d_in[5];
    const float* b1   = (const float*)d_in[6];
    const float* w2   = (const float*)d_in[7];
    const float* b2   = (const float*)d_in[8];
    const float* w3   = (const float*)d_in[9];
    const float* b3   = (const float*)d_in[10];

    float* out = (float*)d_out;
    unsigned short* Wc  = (unsigned short*)d_ws;           // 704*328 bf16
    float*          bcp = (float*)(Wc + WROWS * PITCHW);   // 640

    pack_weights<<<256, 256, 0, stream>>>(w_ih, w_hh, b_ih, b_hh, w1, Wc, bcp);

    lstm_main<<<NBLK, NT, 0, stream>>>(
        x, Wc, bcp, b1, w2, b2, w3, b3,
        out, out + OFF_OUTPUTS, out + OFF_YS);
}